// Round 1
// baseline (1469.573 us; speedup 1.0000x reference)
//
#include <hip/hip_runtime.h>

#define NROWS 65536
#define DIM 64
#define KCODES 8192
#define DECAYF 0.99f
#define EPSV 1e-5f
#define KD (KCODES * DIM)
#define KSPLIT 4

// ws layout (float offsets)
#define WS_PSUM   0          // 256*64 partial sums
#define WS_PSQ    16384      // 256*64 partial sumsq
#define WS_STATS  32768      // mean[64], rstd[64], running_std[64]
#define WS_CK     33024      // 8192 code norms
#define WS_BESTD  41216      // KSPLIT*65536
#define WS_BESTI  303360     // KSPLIT*65536 (int)
#define WS_IDX    565504     // 65536 (int)
#define WS_DW     631040     // 8192*64
#define WS_COUNTS 1155328    // 8192

// ---------------- K1a: per-block column partial sums ----------------
__global__ __launch_bounds__(256) void k_colstats_partial(
    const float* __restrict__ x, float* __restrict__ psum, float* __restrict__ psq)
{
    const int wave = threadIdx.x >> 6;      // 0..3 (subrow)
    const int col  = threadIdx.x & 63;
    const int base = blockIdx.x * 256;      // 256 rows per block
    float s = 0.f, q = 0.f;
    #pragma unroll 4
    for (int i = 0; i < 64; ++i) {
        int r = base + i * 4 + wave;
        float v = x[(size_t)r * DIM + col];
        s += v;
        q += v * v;
    }
    __shared__ float ls[4][64];
    __shared__ float lq[4][64];
    ls[wave][col] = s;
    lq[wave][col] = q;
    __syncthreads();
    if (threadIdx.x < 64) {
        float ts = ls[0][col] + ls[1][col] + ls[2][col] + ls[3][col];
        float tq = lq[0][col] + lq[1][col] + lq[2][col] + lq[3][col];
        psum[blockIdx.x * 64 + col] = ts;
        psq[blockIdx.x * 64 + col]  = tq;
    }
}

// ---------------- K1b: finalize stats ----------------
__global__ void k_colstats_final(const float* __restrict__ psum,
                                 const float* __restrict__ psq,
                                 float* __restrict__ stats)
{
    const int col = threadIdx.x; // 64 threads
    float s = 0.f, q = 0.f;
    for (int i = 0; i < 256; ++i) {
        s += psum[i * 64 + col];
        q += psq[i * 64 + col];
    }
    const float n = (float)NROWS;
    float mean = s / n;
    float var = q / n - mean * mean;
    if (var < 0.f) var = 0.f;
    float rstd = 1.0f / sqrtf(var + EPSV);
    float unbiased = var * (n / (n - 1.0f));
    float run_std = sqrtf(unbiased + EPSV);
    stats[col]       = mean;
    stats[64 + col]  = rstd;
    stats[128 + col] = run_std;
}

// ---------------- K2: code norms ----------------
__global__ __launch_bounds__(256) void k_cknorm(const float* __restrict__ emb,
                                                float* __restrict__ ck)
{
    const int wave = threadIdx.x >> 6, lane = threadIdx.x & 63;
    const int code = blockIdx.x * 4 + wave;
    float v = emb[(size_t)code * DIM + lane];
    float s = v * v;
    #pragma unroll
    for (int o = 32; o > 0; o >>= 1) s += __shfl_xor(s, o, 64);
    if (lane == 0) ck[code] = s;
}

// ---------------- K3: distance argmin (K-split) ----------------
__global__ __launch_bounds__(256) void k_argmin(
    const float* __restrict__ x, const float* __restrict__ emb,
    const float* __restrict__ stats, const float* __restrict__ ck,
    float* __restrict__ bestd, int* __restrict__ besti)
{
    const int row = blockIdx.x * 256 + threadIdx.x;
    const int kchunk = blockIdx.y;                 // 0..KSPLIT-1
    const int k0 = kchunk * (KCODES / KSPLIT);

    // load + normalize row into registers
    float xr[DIM];
    const float* xrow = x + (size_t)row * DIM;
    #pragma unroll
    for (int d = 0; d < DIM; d += 4) {
        float4 v = *(const float4*)(xrow + d);
        xr[d]     = (v.x - stats[d])     * stats[64 + d];
        xr[d + 1] = (v.y - stats[d + 1]) * stats[64 + d + 1];
        xr[d + 2] = (v.z - stats[d + 2]) * stats[64 + d + 2];
        xr[d + 3] = (v.w - stats[d + 3]) * stats[64 + d + 3];
    }

    float best = 3.4e38f;
    int bi = k0;
    const float* __restrict__ ep = emb + (size_t)k0 * DIM;
    const float* __restrict__ cp = ck + k0;
    for (int k = 0; k < KCODES / KSPLIT; k += 4) {
        const float* e0 = ep + (size_t)k * DIM;
        float a0 = 0.f, a1 = 0.f, a2 = 0.f, a3 = 0.f;
        #pragma unroll
        for (int d = 0; d < DIM; ++d) {
            float xv = xr[d];
            a0 = fmaf(xv, e0[d], a0);
            a1 = fmaf(xv, e0[DIM + d], a1);
            a2 = fmaf(xv, e0[2 * DIM + d], a2);
            a3 = fmaf(xv, e0[3 * DIM + d], a3);
        }
        float d0 = cp[k]     - 2.f * a0;
        float d1 = cp[k + 1] - 2.f * a1;
        float d2 = cp[k + 2] - 2.f * a2;
        float d3 = cp[k + 3] - 2.f * a3;
        if (d0 < best) { best = d0; bi = k0 + k; }
        if (d1 < best) { best = d1; bi = k0 + k + 1; }
        if (d2 < best) { best = d2; bi = k0 + k + 2; }
        if (d3 < best) { best = d3; bi = k0 + k + 3; }
    }
    bestd[kchunk * NROWS + row] = best;
    besti[kchunk * NROWS + row] = bi;
}

// ---------------- K3b: merge K-split argmin ----------------
__global__ void k_merge(const float* __restrict__ bd, const int* __restrict__ bi,
                        int* __restrict__ idx)
{
    const int r = blockIdx.x * 256 + threadIdx.x;
    float best = bd[r];
    int b = bi[r];
    #pragma unroll
    for (int c = 1; c < KSPLIT; ++c) {
        float d = bd[c * NROWS + r];
        int  i = bi[c * NROWS + r];
        if (d < best) { best = d; b = i; }
    }
    idx[r] = b;
}

// ---------------- K4: scatter (segment sums) ----------------
__global__ __launch_bounds__(256) void k_scatter(
    const float* __restrict__ x, const float* __restrict__ stats,
    const int* __restrict__ idx, float* __restrict__ dw, float* __restrict__ counts)
{
    const int t = blockIdx.x * 256 + threadIdx.x;
    const int row = t >> 6, col = t & 63;
    const int j = idx[row];
    float xv = (x[(size_t)row * DIM + col] - stats[col]) * stats[64 + col];
    atomicAdd(&dw[(size_t)j * DIM + col], xv);
    if (col == 0) atomicAdd(&counts[j], 1.0f);
}

// ---------------- K5: epilogue ----------------
__global__ __launch_bounds__(256) void k_final(
    const float* __restrict__ emb, const float* __restrict__ cs,
    const float* __restrict__ dw, const float* __restrict__ counts,
    const float* __restrict__ stats, float* __restrict__ out)
{
    const int t = blockIdx.x * 256 + threadIdx.x; // over K*D
    const int k = t >> 6, d = t & 63;
    float csk = cs[k];
    float ns = csk * DECAYF + (1.f - DECAYF) * counts[k];
    float ne = (csk * emb[t] * DECAYF + (1.f - DECAYF) * dw[t]) / ns;
    out[KD + t] = ne;                              // new_emb
    out[t] = ne * stats[128 + d] + stats[d];       // vq_embedding_output
    if (d == 0) out[2 * KD + k] = ns;              // new_size
}

extern "C" void kernel_launch(void* const* d_in, const int* in_sizes, int n_in,
                              void* d_out, int out_size, void* d_ws, size_t ws_size,
                              hipStream_t stream)
{
    const float* x   = (const float*)d_in[0];
    const float* emb = (const float*)d_in[1];
    const float* cs  = (const float*)d_in[2];
    float* out = (float*)d_out;
    float* ws  = (float*)d_ws;

    float* psum   = ws + WS_PSUM;
    float* psq    = ws + WS_PSQ;
    float* stats  = ws + WS_STATS;
    float* ck     = ws + WS_CK;
    float* bestd  = ws + WS_BESTD;
    int*   besti  = (int*)(ws + WS_BESTI);
    int*   idx    = (int*)(ws + WS_IDX);
    float* dw     = ws + WS_DW;
    float* counts = ws + WS_COUNTS;

    // zero the accumulation buffers (dw + counts are contiguous)
    hipMemsetAsync(dw, 0, (size_t)(KD + KCODES) * sizeof(float), stream);

    k_colstats_partial<<<256, 256, 0, stream>>>(x, psum, psq);
    k_colstats_final<<<1, 64, 0, stream>>>(psum, psq, stats);
    k_cknorm<<<KCODES / 4, 256, 0, stream>>>(emb, ck);
    dim3 g3(NROWS / 256, KSPLIT);
    k_argmin<<<g3, 256, 0, stream>>>(x, emb, stats, ck, bestd, besti);
    k_merge<<<NROWS / 256, 256, 0, stream>>>(bestd, besti, idx);
    k_scatter<<<(NROWS * DIM) / 256, 256, 0, stream>>>(x, stats, idx, dw, counts);
    k_final<<<KD / 256, 256, 0, stream>>>(emb, cs, dw, counts, stats, out);
}

// Round 2
// 264.745 us; speedup vs baseline: 5.5509x; 5.5509x over previous
//
#include <hip/hip_runtime.h>

#define NROWS 65536
#define DIM 64
#define KCODES 8192
#define DECAYF 0.99f
#define EPSV 1e-5f
#define KD (KCODES * DIM)

typedef _Float16 half8 __attribute__((ext_vector_type(8)));
typedef float f32x4 __attribute__((ext_vector_type(4)));

// ws layout (float offsets)
#define WS_PSUM   0          // 256*64
#define WS_PSQ    16384      // 256*64
#define WS_STATS  32768      // mean[64], rstd[64], running_std[64] (256 slots)
#define WS_CK     33024      // 8192
#define WS_EBUF   41216      // 524288 floats = 2 MB (64 rounds x 32 KB, pre-swizzled f16 split planes)
#define WS_IDX    565504     // 65536 ints
#define WS_DW     631040     // 8192*64
#define WS_COUNTS 1155328    // 8192

// ---------------- K1a: per-block column partial sums ----------------
__global__ __launch_bounds__(256) void k_colstats_partial(
    const float* __restrict__ x, float* __restrict__ psum, float* __restrict__ psq)
{
    const int wave = threadIdx.x >> 6;
    const int col  = threadIdx.x & 63;
    const int base = blockIdx.x * 256;
    float s = 0.f, q = 0.f;
    #pragma unroll 4
    for (int i = 0; i < 64; ++i) {
        int r = base + i * 4 + wave;
        float v = x[(size_t)r * DIM + col];
        s += v;
        q += v * v;
    }
    __shared__ float ls[4][64];
    __shared__ float lq[4][64];
    ls[wave][col] = s;
    lq[wave][col] = q;
    __syncthreads();
    if (threadIdx.x < 64) {
        psum[blockIdx.x * 64 + col] = ls[0][col] + ls[1][col] + ls[2][col] + ls[3][col];
        psq[blockIdx.x * 64 + col]  = lq[0][col] + lq[1][col] + lq[2][col] + lq[3][col];
    }
}

// ---------------- K1b: finalize stats ----------------
__global__ void k_colstats_final(const float* __restrict__ psum,
                                 const float* __restrict__ psq,
                                 float* __restrict__ stats)
{
    const int col = threadIdx.x; // 64 threads
    float s = 0.f, q = 0.f;
    for (int i = 0; i < 256; ++i) {
        s += psum[i * 64 + col];
        q += psq[i * 64 + col];
    }
    const float n = (float)NROWS;
    float mean = s / n;
    float var = q / n - mean * mean;
    if (var < 0.f) var = 0.f;
    stats[col]       = mean;
    stats[64 + col]  = 1.0f / sqrtf(var + EPSV);
    stats[128 + col] = sqrtf(var * (n / (n - 1.0f)) + EPSV);
}

// ---------------- K2: code norms (exact fp32) ----------------
__global__ __launch_bounds__(256) void k_cknorm(const float* __restrict__ emb,
                                                float* __restrict__ ck)
{
    const int wave = threadIdx.x >> 6, lane = threadIdx.x & 63;
    const int code = blockIdx.x * 4 + wave;
    float v = emb[(size_t)code * DIM + lane];
    float s = v * v;
    #pragma unroll
    for (int o = 32; o > 0; o >>= 1) s += __shfl_xor(s, o, 64);
    if (lane == 0) ck[code] = s;
}

// ---------------- K2b: emb f16 split planes, pre-swizzled for LDS image ----
// layout (half8 units): [round=k/128][tile=(k/16)%8][split][r=k%16][p]
//   p = c ^ (r&7), c = chunk index (8 f16 per chunk), split stride 128, tile stride 256
__global__ __launch_bounds__(256) void k_prep_emb(const float* __restrict__ emb,
                                                  half8* __restrict__ ebuf)
{
    const int tid = blockIdx.x * 256 + threadIdx.x; // 65536 = 8192 codes * 8 chunks
    const int k = tid >> 3, c = tid & 7;
    const float* e = emb + (size_t)k * DIM + c * 8;
    float4 a = *(const float4*)e;
    float4 b = *(const float4*)(e + 4);
    float f[8] = {a.x, a.y, a.z, a.w, b.x, b.y, b.z, b.w};
    half8 h, m;
    #pragma unroll
    for (int i = 0; i < 8; ++i) {
        _Float16 t = (_Float16)f[i];
        h[i] = t;
        m[i] = (_Float16)((f[i] - (float)t) * 2048.0f);
    }
    const int r = k & 15;
    const int p = c ^ (r & 7);
    const size_t base = (size_t)(k >> 7) * 2048 + (size_t)((k >> 4) & 7) * 256 + r * 8;
    ebuf[base + p]       = h;
    ebuf[base + 128 + p] = m;
}

// ---------------- K3: MFMA distance argmin ----------------
// 512 threads = 8 waves; wave owns 16 rows; block = 128 rows; grid 512 blocks.
// Per 16-code tile: acc_hi = xh*eh ; acc_mid = xh*em' + xm'*eh (mid planes x2048)
// dist = ck - 2*acc_hi - acc_mid/1024
__device__ __forceinline__ void gload16(const void* g, void* l)
{
    __builtin_amdgcn_global_load_lds(
        (const __attribute__((address_space(1))) void*)g,
        (__attribute__((address_space(3))) void*)l, 16, 0, 0);
}

__global__ __launch_bounds__(512) void k_argmin_mfma(
    const float* __restrict__ x, const half8* __restrict__ ebuf,
    const float* __restrict__ ck, const float* __restrict__ stats,
    int* __restrict__ idx)
{
    __shared__ half8 smem[4096]; // 64 KB: 2 bufs x 2048 half8 (32 KB rounds)

    const int lane = threadIdx.x & 63;
    const int wave = threadIdx.x >> 6;
    const int row0 = blockIdx.x * 128 + wave * 16;
    const int r = lane & 15;        // code column within tile / A row within tile
    const int g = lane >> 4;        // lane group -> k-chunk
    const int rm = r & 7;

    // ---- build A fragments in registers (normalize + fp16 split) ----
    const int dbase = g * 8;
    const float* xrow = x + (size_t)(row0 + r) * DIM + dbase;
    float4 xa = *(const float4*)(xrow);
    float4 xb = *(const float4*)(xrow + 4);
    float4 xc = *(const float4*)(xrow + 32);
    float4 xd = *(const float4*)(xrow + 36);
    float4 m0 = *(const float4*)(stats + dbase);
    float4 m1 = *(const float4*)(stats + 32 + dbase);
    float4 s0 = *(const float4*)(stats + 64 + dbase);
    float4 s1 = *(const float4*)(stats + 96 + dbase);

    float xn0[8] = {(xa.x - m0.x) * s0.x, (xa.y - m0.y) * s0.y,
                    (xa.z - m0.z) * s0.z, (xa.w - m0.w) * s0.w,
                    (xb.x - m0.x) * s0.x, (xb.y - m0.y) * s0.y,
                    (xb.z - m0.z) * s0.z, (xb.w - m0.w) * s0.w};
    // careful: xb covers d = dbase+4.. -> stats at dbase+4
    float4 m0b = *(const float4*)(stats + dbase + 4);
    float4 s0b = *(const float4*)(stats + 64 + dbase + 4);
    xn0[4] = (xb.x - m0b.x) * s0b.x; xn0[5] = (xb.y - m0b.y) * s0b.y;
    xn0[6] = (xb.z - m0b.z) * s0b.z; xn0[7] = (xb.w - m0b.w) * s0b.w;
    float4 m1b = *(const float4*)(stats + 32 + dbase + 4);
    float4 s1b = *(const float4*)(stats + 96 + dbase + 4);
    float xn1[8] = {(xc.x - m1.x) * s1.x, (xc.y - m1.y) * s1.y,
                    (xc.z - m1.z) * s1.z, (xc.w - m1.w) * s1.w,
                    (xd.x - m1b.x) * s1b.x, (xd.y - m1b.y) * s1b.y,
                    (xd.z - m1b.z) * s1b.z, (xd.w - m1b.w) * s1b.w};

    half8 ah0, am0, ah1, am1;
    #pragma unroll
    for (int i = 0; i < 8; ++i) {
        _Float16 t0 = (_Float16)xn0[i];
        ah0[i] = t0;
        am0[i] = (_Float16)((xn0[i] - (float)t0) * 2048.0f);
        _Float16 t1 = (_Float16)xn1[i];
        ah1[i] = t1;
        am1[i] = (_Float16)((xn1[i] - (float)t1) * 2048.0f);
    }

    float best[4] = {3.4e38f, 3.4e38f, 3.4e38f, 3.4e38f};
    int bidx[4] = {0, 0, 0, 0};

    // ---- prologue stage ----
    {
        const char* src = (const char*)ebuf + threadIdx.x * 16;
        char* dst = (char*)smem + threadIdx.x * 16;
        #pragma unroll
        for (int j = 0; j < 4; ++j) gload16(src + j * 8192, dst + j * 8192);
    }
    __syncthreads();

    for (int t = 0; t < 64; ++t) {
        const int buf = t & 1;
        if (t < 63) {
            const char* src = (const char*)ebuf + (size_t)(t + 1) * 32768 + threadIdx.x * 16;
            char* dst = (char*)smem + (buf ^ 1) * 32768 + threadIdx.x * 16;
            #pragma unroll
            for (int j = 0; j < 4; ++j) gload16(src + j * 8192, dst + j * 8192);
        }
        #pragma unroll
        for (int tile = 0; tile < 8; ++tile) {
            const int base = buf * 2048 + tile * 256 + r * 8;
            half8 bh0 = smem[base + (g ^ rm)];
            half8 bh1 = smem[base + ((g + 4) ^ rm)];
            half8 bm0 = smem[base + 128 + (g ^ rm)];
            half8 bm1 = smem[base + 128 + ((g + 4) ^ rm)];
            const int code0 = t * 128 + tile * 16;
            float ckv = ck[code0 + r];
            f32x4 acch = {0.f, 0.f, 0.f, 0.f};
            f32x4 accm = {0.f, 0.f, 0.f, 0.f};
            acch = __builtin_amdgcn_mfma_f32_16x16x32_f16(ah0, bh0, acch, 0, 0, 0);
            acch = __builtin_amdgcn_mfma_f32_16x16x32_f16(ah1, bh1, acch, 0, 0, 0);
            accm = __builtin_amdgcn_mfma_f32_16x16x32_f16(ah0, bm0, accm, 0, 0, 0);
            accm = __builtin_amdgcn_mfma_f32_16x16x32_f16(ah1, bm1, accm, 0, 0, 0);
            accm = __builtin_amdgcn_mfma_f32_16x16x32_f16(am0, bh0, accm, 0, 0, 0);
            accm = __builtin_amdgcn_mfma_f32_16x16x32_f16(am1, bh1, accm, 0, 0, 0);
            #pragma unroll
            for (int q = 0; q < 4; ++q) {
                float d = fmaf(accm[q], -9.765625e-4f, fmaf(acch[q], -2.0f, ckv));
                if (d < best[q]) { best[q] = d; bidx[q] = code0 + r; }
            }
        }
        __syncthreads();
    }

    // ---- cross-lane argmin over the 16 code columns ----
    #pragma unroll
    for (int off = 1; off < 16; off <<= 1) {
        #pragma unroll
        for (int q = 0; q < 4; ++q) {
            float od = __shfl_xor(best[q], off, 64);
            int oi = __shfl_xor(bidx[q], off, 64);
            if (od < best[q] || (od == best[q] && oi < bidx[q])) {
                best[q] = od; bidx[q] = oi;
            }
        }
    }
    if (r == 0) {
        int4 v = {bidx[0], bidx[1], bidx[2], bidx[3]};
        *(int4*)(idx + row0 + g * 4) = v; // rows row0 + g*4 + q  (C row = g*4 + reg)
    }
}

// ---------------- K4: scatter (segment sums) ----------------
__global__ __launch_bounds__(256) void k_scatter(
    const float* __restrict__ x, const float* __restrict__ stats,
    const int* __restrict__ idx, float* __restrict__ dw, float* __restrict__ counts)
{
    const int t = blockIdx.x * 256 + threadIdx.x;
    const int row = t >> 6, col = t & 63;
    const int j = idx[row];
    float xv = (x[(size_t)row * DIM + col] - stats[col]) * stats[64 + col];
    atomicAdd(&dw[(size_t)j * DIM + col], xv);
    if (col == 0) atomicAdd(&counts[j], 1.0f);
}

// ---------------- K5: epilogue ----------------
__global__ __launch_bounds__(256) void k_final(
    const float* __restrict__ emb, const float* __restrict__ cs,
    const float* __restrict__ dw, const float* __restrict__ counts,
    const float* __restrict__ stats, float* __restrict__ out)
{
    const int t = blockIdx.x * 256 + threadIdx.x; // over K*D
    const int k = t >> 6, d = t & 63;
    float csk = cs[k];
    float ns = csk * DECAYF + (1.f - DECAYF) * counts[k];
    float ne = (csk * emb[t] * DECAYF + (1.f - DECAYF) * dw[t]) / ns;
    out[KD + t] = ne;
    out[t] = ne * stats[128 + d] + stats[d];
    if (d == 0) out[2 * KD + k] = ns;
}

extern "C" void kernel_launch(void* const* d_in, const int* in_sizes, int n_in,
                              void* d_out, int out_size, void* d_ws, size_t ws_size,
                              hipStream_t stream)
{
    const float* x   = (const float*)d_in[0];
    const float* emb = (const float*)d_in[1];
    const float* cs  = (const float*)d_in[2];
    float* out = (float*)d_out;
    float* ws  = (float*)d_ws;

    float* psum   = ws + WS_PSUM;
    float* psq    = ws + WS_PSQ;
    float* stats  = ws + WS_STATS;
    float* ck     = ws + WS_CK;
    half8* ebuf   = (half8*)(ws + WS_EBUF);
    int*   idx    = (int*)(ws + WS_IDX);
    float* dw     = ws + WS_DW;
    float* counts = ws + WS_COUNTS;

    hipMemsetAsync(dw, 0, (size_t)(KD + KCODES) * sizeof(float), stream);

    k_colstats_partial<<<256, 256, 0, stream>>>(x, psum, psq);
    k_colstats_final<<<1, 64, 0, stream>>>(psum, psq, stats);
    k_cknorm<<<KCODES / 4, 256, 0, stream>>>(emb, ck);
    k_prep_emb<<<256, 256, 0, stream>>>(emb, ebuf);
    k_argmin_mfma<<<NROWS / 128, 512, 0, stream>>>(x, ebuf, ck, stats, idx);
    k_scatter<<<(NROWS * DIM) / 256, 256, 0, stream>>>(x, stats, idx, dw, counts);
    k_final<<<KD / 256, 256, 0, stream>>>(emb, cs, dw, counts, stats, out);
}

// Round 3
// 215.415 us; speedup vs baseline: 6.8220x; 1.2290x over previous
//
#include <hip/hip_runtime.h>

#define NROWS 65536
#define DIM 64
#define KCODES 8192
#define DECAYF 0.99f
#define EPSV 1e-5f
#define KD (KCODES * DIM)
#define KSPLIT 2
#define KC (KCODES / KSPLIT)   // 4096 codes per split chunk
#define ROUNDS 32               // KC / 128 codes per staged round (16 KB)

typedef _Float16 half8 __attribute__((ext_vector_type(8)));
typedef float f32x16 __attribute__((ext_vector_type(16)));

// ws layout (float offsets)
#define WS_PSUM   0          // 256*64
#define WS_PSQ    16384      // 256*64
#define WS_STATS  32768      // mean[64], rstd[64], running_std[64]
#define WS_CK     33024      // 8192
#define WS_EBUF   41216      // 8192 codes * 64 dims f16 = 262144 floats (1 MB)
#define WS_WBEST  303360     // KSPLIT*65536
#define WS_ICODE  434432     // KSPLIT*65536 (int)
#define WS_IDX    565504     // 65536 (int)
#define WS_DW     631040     // 8192*64
#define WS_COUNTS 1155328    // 8192

// ---------------- K1a: per-block column partial sums ----------------
__global__ __launch_bounds__(256) void k_colstats_partial(
    const float* __restrict__ x, float* __restrict__ psum, float* __restrict__ psq)
{
    const int wave = threadIdx.x >> 6;
    const int col  = threadIdx.x & 63;
    const int base = blockIdx.x * 256;
    float s = 0.f, q = 0.f;
    #pragma unroll 4
    for (int i = 0; i < 64; ++i) {
        int r = base + i * 4 + wave;
        float v = x[(size_t)r * DIM + col];
        s += v;
        q += v * v;
    }
    __shared__ float ls[4][64];
    __shared__ float lq[4][64];
    ls[wave][col] = s;
    lq[wave][col] = q;
    __syncthreads();
    if (threadIdx.x < 64) {
        psum[blockIdx.x * 64 + col] = ls[0][col] + ls[1][col] + ls[2][col] + ls[3][col];
        psq[blockIdx.x * 64 + col]  = lq[0][col] + lq[1][col] + lq[2][col] + lq[3][col];
    }
}

// ---------------- K1b: finalize stats ----------------
__global__ void k_colstats_final(const float* __restrict__ psum,
                                 const float* __restrict__ psq,
                                 float* __restrict__ stats)
{
    const int col = threadIdx.x; // 64 threads
    float s = 0.f, q = 0.f;
    for (int i = 0; i < 256; ++i) {
        s += psum[i * 64 + col];
        q += psq[i * 64 + col];
    }
    const float n = (float)NROWS;
    float mean = s / n;
    float var = q / n - mean * mean;
    if (var < 0.f) var = 0.f;
    stats[col]       = mean;
    stats[64 + col]  = 1.0f / sqrtf(var + EPSV);
    stats[128 + col] = sqrtf(var * (n / (n - 1.0f)) + EPSV);
}

// ---------------- K2: prep emb (f16 centered plane, staged layout) + ck ----
// ebuf layout (half8 units): idx = R*1024 + t*256 + c*64 + h*32 + col
//   code = R*128 + t*32 + col ; element dims = c*16 + h*8 + j
__global__ __launch_bounds__(256) void k_prep(const float* __restrict__ emb,
                                              half8* __restrict__ ebuf,
                                              float* __restrict__ ck)
{
    const int tid = blockIdx.x * 256 + threadIdx.x;   // 65536 = 8192 codes * 8
    const int code = tid >> 3, sub = tid & 7;
    const int c = sub >> 1, h = sub & 1;
    const int d0 = c * 16 + h * 8;
    const float* e = emb + (size_t)code * DIM + d0;
    float4 a = *(const float4*)e;
    float4 b = *(const float4*)(e + 4);
    float f[8] = {a.x, a.y, a.z, a.w, b.x, b.y, b.z, b.w};
    half8 hh;
    float ssq = 0.f;
    #pragma unroll
    for (int i = 0; i < 8; ++i) {
        hh[i] = (_Float16)(f[i] - 0.5f);   // centered: halves f16 quantization err
        ssq += f[i] * f[i];
    }
    #pragma unroll
    for (int o = 1; o < 8; o <<= 1) ssq += __shfl_xor(ssq, o, 64);
    if (sub == 0) ck[code] = ssq;
    const int R = code >> 7, t = (code >> 5) & 3, col = code & 31;
    ebuf[(size_t)R * 1024 + t * 256 + c * 64 + h * 32 + col] = hh;
}

// ---------------- K3: 32x32 MFMA distance argmin ----------------
__device__ __forceinline__ void gload16(const void* g, void* l)
{
    __builtin_amdgcn_global_load_lds(
        (const __attribute__((address_space(1))) void*)g,
        (__attribute__((address_space(3))) void*)l, 16, 0, 0);
}

// 256 thr = 4 waves; wave owns 32 rows; block = 128 rows x 4096 codes (kc chunk).
// grid = (NROWS/128, KSPLIT). Maximizes w = xn.(e-0.5) - ck/2  (== argmin dist).
__global__ __launch_bounds__(256, 3) void k_argmin32(
    const float* __restrict__ x, const half8* __restrict__ ebuf,
    const float* __restrict__ ck, const float* __restrict__ stats,
    float* __restrict__ wbest, int* __restrict__ icode)
{
    __shared__ half8 smem[2048];   // 32 KB: 2 x 16 KB rounds

    const int lane = threadIdx.x & 63;
    const int wave = threadIdx.x >> 6;
    const int kc = blockIdx.y;
    const int col = lane & 31, h = lane >> 5;
    const int myrow = blockIdx.x * 128 + wave * 32 + col;

    // ---- A fragments: xh (f16) + xm (residual, unscaled f16) ----
    half8 ah[4], am[4];
    {
        const float* xr = x + (size_t)myrow * DIM + h * 8;
        #pragma unroll
        for (int c = 0; c < 4; ++c) {
            float4 v0  = *(const float4*)(xr + c * 16);
            float4 v1  = *(const float4*)(xr + c * 16 + 4);
            float4 mu0 = *(const float4*)(stats + h * 8 + c * 16);
            float4 mu1 = *(const float4*)(stats + h * 8 + c * 16 + 4);
            float4 sg0 = *(const float4*)(stats + 64 + h * 8 + c * 16);
            float4 sg1 = *(const float4*)(stats + 64 + h * 8 + c * 16 + 4);
            float xn[8] = {(v0.x - mu0.x) * sg0.x, (v0.y - mu0.y) * sg0.y,
                           (v0.z - mu0.z) * sg0.z, (v0.w - mu0.w) * sg0.w,
                           (v1.x - mu1.x) * sg1.x, (v1.y - mu1.y) * sg1.y,
                           (v1.z - mu1.z) * sg1.z, (v1.w - mu1.w) * sg1.w};
            #pragma unroll
            for (int j = 0; j < 8; ++j) {
                _Float16 t = (_Float16)xn[j];
                ah[c][j] = t;
                am[c][j] = (_Float16)(xn[j] - (float)t);
            }
        }
    }

    float best[16];
    int bcode[16];
    #pragma unroll
    for (int i = 0; i < 16; ++i) { best[i] = -3.4e38f; bcode[i] = 0; }

    const half8* esrc = ebuf + (size_t)kc * (KC * 8);   // 8 half8 per code
    const float* ckb = ck + kc * KC;

    // prologue stage
    {
        const char* src = (const char*)esrc + threadIdx.x * 16;
        char* dst = (char*)smem + threadIdx.x * 16;
        #pragma unroll
        for (int i = 0; i < 4; ++i) gload16(src + i * 4096, dst + i * 4096);
    }
    __syncthreads();

    for (int R = 0; R < ROUNDS; ++R) {
        const int buf = R & 1;
        if (R < ROUNDS - 1) {
            const char* src = (const char*)esrc + (size_t)(R + 1) * 16384 + threadIdx.x * 16;
            char* dst = (char*)smem + (buf ^ 1) * 16384 + threadIdx.x * 16;
            #pragma unroll
            for (int i = 0; i < 4; ++i) gload16(src + i * 4096, dst + i * 4096);
        }
        float nhck[4];
        #pragma unroll
        for (int t = 0; t < 4; ++t) nhck[t] = -0.5f * ckb[R * 128 + t * 32 + col];

        const half8* sb = smem + buf * 1024 + lane;
        #pragma unroll
        for (int t = 0; t < 4; ++t) {
            half8 b0 = sb[t * 256];
            half8 b1 = sb[t * 256 + 64];
            half8 b2 = sb[t * 256 + 128];
            half8 b3 = sb[t * 256 + 192];
            f32x16 acc;
            #pragma unroll
            for (int i = 0; i < 16; ++i) acc[i] = nhck[t];
            acc = __builtin_amdgcn_mfma_f32_32x32x16_f16(ah[0], b0, acc, 0, 0, 0);
            acc = __builtin_amdgcn_mfma_f32_32x32x16_f16(ah[1], b1, acc, 0, 0, 0);
            acc = __builtin_amdgcn_mfma_f32_32x32x16_f16(ah[2], b2, acc, 0, 0, 0);
            acc = __builtin_amdgcn_mfma_f32_32x32x16_f16(ah[3], b3, acc, 0, 0, 0);
            acc = __builtin_amdgcn_mfma_f32_32x32x16_f16(am[0], b0, acc, 0, 0, 0);
            acc = __builtin_amdgcn_mfma_f32_32x32x16_f16(am[1], b1, acc, 0, 0, 0);
            acc = __builtin_amdgcn_mfma_f32_32x32x16_f16(am[2], b2, acc, 0, 0, 0);
            acc = __builtin_amdgcn_mfma_f32_32x32x16_f16(am[3], b3, acc, 0, 0, 0);
            const int codeb = R * 128 + t * 32 + col;
            #pragma unroll
            for (int i = 0; i < 16; ++i) {
                if (acc[i] > best[i]) { best[i] = acc[i]; bcode[i] = codeb; }
            }
        }
        __syncthreads();
    }

    // cross-lane argmax over the 32 code columns (xor<32 stays within half-wave)
    #pragma unroll
    for (int off = 1; off < 32; off <<= 1) {
        #pragma unroll
        for (int i = 0; i < 16; ++i) {
            float ow = __shfl_xor(best[i], off, 64);
            int oc = __shfl_xor(bcode[i], off, 64);
            if (ow > best[i] || (ow == best[i] && oc < bcode[i])) {
                best[i] = ow; bcode[i] = oc;
            }
        }
    }
    if (col == 0) {
        const int rbase = blockIdx.x * 128 + wave * 32 + 4 * h;
        #pragma unroll
        for (int i = 0; i < 16; ++i) {
            int row = rbase + (i & 3) + 8 * (i >> 2);
            wbest[(size_t)kc * NROWS + row] = best[i];
            icode[(size_t)kc * NROWS + row] = bcode[i] + kc * KC;
        }
    }
}

// ---------------- K3b: merge KSPLIT chunks + counts ----------------
__global__ __launch_bounds__(256) void k_merge(
    const float* __restrict__ wbest, const int* __restrict__ icode,
    int* __restrict__ idx, float* __restrict__ counts)
{
    const int r = blockIdx.x * 256 + threadIdx.x;
    float w0 = wbest[r];         int c0 = icode[r];
    float w1 = wbest[NROWS + r]; int c1 = icode[NROWS + r];
    int j = (w1 > w0) ? c1 : c0;   // tie -> chunk 0 (smaller index)
    idx[r] = j;
    atomicAdd(&counts[j], 1.0f);
}

// ---------------- K4: scatter (segment sums) ----------------
__global__ __launch_bounds__(256) void k_scatter(
    const float* __restrict__ x, const float* __restrict__ stats,
    const int* __restrict__ idx, float* __restrict__ dw)
{
    const int t = blockIdx.x * 256 + threadIdx.x;
    const int row = t >> 6, col = t & 63;
    const int j = idx[row];
    float xv = (x[(size_t)row * DIM + col] - stats[col]) * stats[64 + col];
    atomicAdd(&dw[(size_t)j * DIM + col], xv);
}

// ---------------- K5: epilogue ----------------
__global__ __launch_bounds__(256) void k_final(
    const float* __restrict__ emb, const float* __restrict__ cs,
    const float* __restrict__ dw, const float* __restrict__ counts,
    const float* __restrict__ stats, float* __restrict__ out)
{
    const int t = blockIdx.x * 256 + threadIdx.x; // over K*D
    const int k = t >> 6, d = t & 63;
    float csk = cs[k];
    float ns = csk * DECAYF + (1.f - DECAYF) * counts[k];
    float ne = (csk * emb[t] * DECAYF + (1.f - DECAYF) * dw[t]) / ns;
    out[KD + t] = ne;
    out[t] = ne * stats[128 + d] + stats[d];
    if (d == 0) out[2 * KD + k] = ns;
}

extern "C" void kernel_launch(void* const* d_in, const int* in_sizes, int n_in,
                              void* d_out, int out_size, void* d_ws, size_t ws_size,
                              hipStream_t stream)
{
    const float* x   = (const float*)d_in[0];
    const float* emb = (const float*)d_in[1];
    const float* cs  = (const float*)d_in[2];
    float* out = (float*)d_out;
    float* ws  = (float*)d_ws;

    float* psum   = ws + WS_PSUM;
    float* psq    = ws + WS_PSQ;
    float* stats  = ws + WS_STATS;
    float* ck     = ws + WS_CK;
    half8* ebuf   = (half8*)(ws + WS_EBUF);
    float* wbest  = ws + WS_WBEST;
    int*   icode  = (int*)(ws + WS_ICODE);
    int*   idx    = (int*)(ws + WS_IDX);
    float* dw     = ws + WS_DW;
    float* counts = ws + WS_COUNTS;

    hipMemsetAsync(dw, 0, (size_t)(KD + KCODES) * sizeof(float), stream);

    k_colstats_partial<<<256, 256, 0, stream>>>(x, psum, psq);
    k_colstats_final<<<1, 64, 0, stream>>>(psum, psq, stats);
    k_prep<<<256, 256, 0, stream>>>(emb, ebuf, ck);
    dim3 g3(NROWS / 128, KSPLIT);
    k_argmin32<<<g3, 256, 0, stream>>>(x, ebuf, ck, stats, wbest, icode);
    k_merge<<<NROWS / 256, 256, 0, stream>>>(wbest, icode, idx, counts);
    k_scatter<<<(NROWS * DIM) / 256, 256, 0, stream>>>(x, stats, idx, dw);
    k_final<<<KD / 256, 256, 0, stream>>>(emb, cs, dw, counts, stats, out);
}